// Round 11
// baseline (693.049 us; speedup 1.0000x reference)
//
#include <hip/hip_runtime.h>
#include <hip/hip_bf16.h>
#include <cmath>

#define NN 50000
#define NE 800000
#define NBLK_SCAN 196  // ceil(NN/256)

typedef __attribute__((ext_vector_type(4))) float f32x4;
typedef __attribute__((ext_vector_type(8))) short bfx8;

__device__ inline ushort f2bf(float x) {
  return __bfloat16_as_ushort(__float2bfloat16(x));
}

// Raw barrier: lgkmcnt(0) + s_barrier, no vmcnt drain (keeps prefetch loads in flight).
#define BAR_NODRAIN() asm volatile("s_waitcnt lgkmcnt(0)\ns_barrier" ::: "memory")

// ---------------- CSR build ----------------
__global__ void count_kernel(const int* __restrict__ dst, unsigned int* __restrict__ cnt) {
  int e = blockIdx.x * 256 + threadIdx.x;
  if (e < NE) atomicAdd(&cnt[dst[e]], 1u);
}

__global__ void partial_kernel(const unsigned int* __restrict__ cnt,
                               unsigned int* __restrict__ bsum) {
  __shared__ unsigned int s[256];
  const int t = threadIdx.x;
  const int i = blockIdx.x * 256 + t;
  s[t] = (i < NN) ? cnt[i] : 0u;
  __syncthreads();
#pragma unroll
  for (int o = 128; o > 0; o >>= 1) {
    if (t < o) s[t] += s[t + o];
    __syncthreads();
  }
  if (t == 0) bsum[blockIdx.x] = s[0];
}

__global__ void scanb_kernel(unsigned int* __restrict__ bsum) {
  __shared__ unsigned int s[256];
  const int t = threadIdx.x;
  const unsigned int v = (t < NBLK_SCAN) ? bsum[t] : 0u;
  s[t] = v;
  __syncthreads();
  for (int o = 1; o < 256; o <<= 1) {
    unsigned int u = (t >= o) ? s[t - o] : 0u;
    __syncthreads();
    s[t] += u;
    __syncthreads();
  }
  if (t < NBLK_SCAN) bsum[t] = s[t] - v;  // exclusive
}

__global__ void apply_kernel(unsigned int* __restrict__ cnt,
                             const unsigned int* __restrict__ bsum,
                             unsigned int* __restrict__ rowstart) {
  __shared__ unsigned int s[256];
  const int t = threadIdx.x;
  const int i = blockIdx.x * 256 + t;
  const unsigned int v = (i < NN) ? cnt[i] : 0u;
  s[t] = v;
  __syncthreads();
  for (int o = 1; o < 256; o <<= 1) {
    unsigned int u = (t >= o) ? s[t - o] : 0u;
    __syncthreads();
    s[t] += u;
    __syncthreads();
  }
  const unsigned int excl = s[t] - v + bsum[blockIdx.x];
  if (i < NN) {
    rowstart[i] = excl;
    cnt[i] = excl;  // cursor
    if (i == NN - 1) rowstart[NN] = excl + v;
  }
}

__global__ void bucket_kernel(const int* __restrict__ src, const int* __restrict__ dst,
                              unsigned int* __restrict__ cursor, int* __restrict__ esrc) {
  int e = blockIdx.x * 256 + threadIdx.x;
  if (e < NE) {
    unsigned int pos = atomicAdd(&cursor[dst[e]], 1u);
    esrc[pos] = src[e];
  }
}

// ---------------- weight pre-convert: f32 -> bf16 hi/lo ----------------
__global__ void wconv_kernel(const float* __restrict__ w, ushort* __restrict__ hi,
                             ushort* __restrict__ lo, int count) {
  int i = blockIdx.x * 256 + threadIdx.x;
  if (i < count) {
    float x = w[i];
    ushort h = f2bf(x);
    float hf = __uint_as_float(((unsigned int)h) << 16);
    hi[i] = h;
    lo[i] = f2bf(x - hf);
  }
}

// ---------------- aggregate: S[n] = mean over edges of A[src] ----------------
__global__ __launch_bounds__(256) void aggregate_kernel(const float* __restrict__ A,
                                                        const int* __restrict__ esrc,
                                                        const unsigned int* __restrict__ rowstart,
                                                        float* __restrict__ S) {
  const int t = blockIdx.x * 256 + threadIdx.x;
  const int node = t >> 5;
  const int lane = t & 31;
  if (node >= NN) return;
  const unsigned int rs = rowstart[node], re = rowstart[node + 1];
  f32x4 acc = (f32x4){0.f, 0.f, 0.f, 0.f};
  unsigned int j = rs;
  for (; j + 4 <= re; j += 4) {
    const int s0 = esrc[j], s1 = esrc[j + 1], s2 = esrc[j + 2], s3 = esrc[j + 3];
    const f32x4 v0 = *(const f32x4*)&A[(size_t)s0 * 128 + lane * 4];
    const f32x4 v1 = *(const f32x4*)&A[(size_t)s1 * 128 + lane * 4];
    const f32x4 v2 = *(const f32x4*)&A[(size_t)s2 * 128 + lane * 4];
    const f32x4 v3 = *(const f32x4*)&A[(size_t)s3 * 128 + lane * 4];
    acc += (v0 + v1) + (v2 + v3);
  }
  for (; j < re; ++j) {
    const int s = esrc[j];
    acc += *(const f32x4*)&A[(size_t)s * 128 + lane * 4];
  }
  const float inv = 1.0f / fmaxf((float)(re - rs), 1.0f);
  *(f32x4*)&S[(size_t)node * 128 + lane * 4] = acc * inv;
}

// ---------------- linm (MFMA): out = act(in @ W^T + b), [NN,128]x[128,128] ----------------
template <int RELU>
__global__ __launch_bounds__(256, 3) void linm_kernel(const float* __restrict__ in,
                                                      const ushort* __restrict__ Whi,
                                                      const ushort* __restrict__ Wlo,
                                                      const float* __restrict__ bias,
                                                      float* __restrict__ out) {
  __shared__ __align__(16) ushort Ahi[64 * 64];
  __shared__ __align__(16) ushort Alo[64 * 64];
  __shared__ __align__(16) ushort Bhi[128 * 64];
  __shared__ __align__(16) ushort Blo[128 * 64];
  __shared__ float bs[128];

  const int tid = threadIdx.x;
  const int nb = blockIdx.x * 64;
  const int lane = tid & 63;
  const int wv = tid >> 6;
  const int cl = lane & 15;
  const int kg = lane >> 4;

  if (tid < 128) bs[tid] = bias[tid];

  f32x4 aP[4];
  bfx8 bP[2][8];

#pragma unroll
  for (int q = 0; q < 2; ++q) {
    const int task = tid + q * 256, row = task >> 3, g = task & 7;
    const int n = min(nb + row, NN - 1);
    aP[q * 2 + 0] = __builtin_nontemporal_load((const f32x4*)&in[(size_t)n * 128 + g * 8]);
    aP[q * 2 + 1] = __builtin_nontemporal_load((const f32x4*)&in[(size_t)n * 128 + g * 8 + 4]);
  }
#pragma unroll
  for (int q = 0; q < 4; ++q) {
    const int task = tid + q * 256, o = task >> 3, g = task & 7;
    bP[0][q * 2 + 0] = *(const bfx8*)&Whi[o * 128 + g * 8];
    bP[0][q * 2 + 1] = *(const bfx8*)&Wlo[o * 128 + g * 8];
  }

  f32x4 acc[4][2];
#pragma unroll
  for (int m = 0; m < 4; ++m)
#pragma unroll
    for (int f = 0; f < 2; ++f) acc[m][f] = (f32x4){0.f, 0.f, 0.f, 0.f};

#pragma unroll
  for (int c = 0; c < 2; ++c) {
    BAR_NODRAIN();
    {
#pragma unroll
      for (int q = 0; q < 2; ++q) {
        const int task = tid + q * 256, row = task >> 3, g = task & 7;
        const f32x4 v0 = aP[q * 2 + 0], v1 = aP[q * 2 + 1];
        const float vv[8] = {v0[0], v0[1], v0[2], v0[3], v1[0], v1[1], v1[2], v1[3]};
        bfx8 hv, lv;
#pragma unroll
        for (int i = 0; i < 8; ++i) {
          ushort h = f2bf(vv[i]);
          float hf = __uint_as_float(((unsigned int)h) << 16);
          hv[i] = (short)h;
          lv[i] = (short)f2bf(vv[i] - hf);
        }
        const int gsw = (g ^ (row & 7)) * 8;
        *(bfx8*)&Ahi[row * 64 + gsw] = hv;
        *(bfx8*)&Alo[row * 64 + gsw] = lv;
      }
    }
    {
#pragma unroll
      for (int q = 0; q < 4; ++q) {
        const int task = tid + q * 256, o = task >> 3, g = task & 7;
        const int gsw = (g ^ (o & 7)) * 8;
        *(bfx8*)&Bhi[o * 64 + gsw] = bP[c][q * 2 + 0];
        *(bfx8*)&Blo[o * 64 + gsw] = bP[c][q * 2 + 1];
      }
    }
    if (c == 0) {
#pragma unroll
      for (int q = 0; q < 2; ++q) {
        const int task = tid + q * 256, row = task >> 3, g = task & 7;
        const int n = min(nb + row, NN - 1);
        aP[q * 2 + 0] = __builtin_nontemporal_load((const f32x4*)&in[(size_t)n * 128 + 64 + g * 8]);
        aP[q * 2 + 1] = __builtin_nontemporal_load((const f32x4*)&in[(size_t)n * 128 + 64 + g * 8 + 4]);
      }
#pragma unroll
      for (int q = 0; q < 4; ++q) {
        const int task = tid + q * 256, o = task >> 3, g = task & 7;
        bP[1][q * 2 + 0] = *(const bfx8*)&Whi[o * 128 + 64 + g * 8];
        bP[1][q * 2 + 1] = *(const bfx8*)&Wlo[o * 128 + 64 + g * 8];
      }
    }
    BAR_NODRAIN();
#pragma unroll
    for (int ks = 0; ks < 2; ++ks) {
      bfx8 ah[4], al[4];
#pragma unroll
      for (int m = 0; m < 4; ++m) {
        const int ar = m * 16 + cl;
        const int gi = ((ks * 4 + kg) ^ (ar & 7)) * 8;
        ah[m] = *(const bfx8*)&Ahi[ar * 64 + gi];
        al[m] = *(const bfx8*)&Alo[ar * 64 + gi];
      }
#pragma unroll
      for (int f = 0; f < 2; ++f) {
        const int o = wv * 32 + f * 16 + cl;
        const int gi = ((ks * 4 + kg) ^ (o & 7)) * 8;
        const bfx8 bh = *(const bfx8*)&Bhi[o * 64 + gi];
        const bfx8 bl = *(const bfx8*)&Blo[o * 64 + gi];
#pragma unroll
        for (int m = 0; m < 4; ++m) {
          acc[m][f] = __builtin_amdgcn_mfma_f32_16x16x32_bf16(ah[m], bh, acc[m][f], 0, 0, 0);
          acc[m][f] = __builtin_amdgcn_mfma_f32_16x16x32_bf16(ah[m], bl, acc[m][f], 0, 0, 0);
          acc[m][f] = __builtin_amdgcn_mfma_f32_16x16x32_bf16(al[m], bh, acc[m][f], 0, 0, 0);
        }
      }
    }
  }

#pragma unroll
  for (int m = 0; m < 4; ++m) {
#pragma unroll
    for (int r = 0; r < 4; ++r) {
      const int node = m * 16 + kg * 4 + r;
      const int n = nb + node;
      if (n >= NN) continue;
#pragma unroll
      for (int f = 0; f < 2; ++f) {
        const int col = wv * 32 + f * 16 + cl;
        float v = acc[m][f][r] + bs[col];
        if (RELU) v = fmaxf(v, 0.f);
        out[(size_t)n * 128 + col] = v;
      }
    }
  }
}

// ---------------- update v4 (MFMA): B direct from global (L2), barrier-free main loop ----
// 512 threads = 8 waves (2M x 4N). A [64][256] hi/lo staged ONCE in LDS (64KB, ~70KB tot
// -> 2 blocks/CU). B fragments are per-lane global loads (weights L2-resident); no B LDS,
// no in-loop barriers — waves free-run, compiler pipelines B-loads under MFMA.
__global__ __launch_bounds__(512, 4) void update_kernel(
    const float* __restrict__ xin, const float* __restrict__ S,
    const float* __restrict__ gw, const float* __restrict__ gb,
    const ushort* __restrict__ Whi, const ushort* __restrict__ Wlo,
    const float* __restrict__ aggb, float* __restrict__ hout) {
  __shared__ __align__(16) ushort Ahi[64 * 256];  // 32KB
  __shared__ __align__(16) ushort Alo[64 * 256];  // 32KB
  __shared__ float wgs[1024];
  __shared__ float gbs[4];
  __shared__ float aggbs[512];
  __shared__ float gts[256];
  __shared__ float red[4 * 64];

  const int tid = threadIdx.x;
  const int nb = blockIdx.x * 64;
  const int lane = tid & 63;
  const int wv = tid >> 6;  // 0..7
  const int wr = wv >> 2;   // M-group 0..1
  const int wc = wv & 3;    // N-group 0..3
  const int cl = lane & 15;
  const int kg = lane >> 4;

  for (int i = tid; i < 1024; i += 512) wgs[i] = gw[i];
  if (tid < 512) aggbs[tid] = aggb[tid];
  if (tid < 4) gbs[tid] = gb[tid];

  // ---- stage A (once): global -> f32, convert hi/lo, swizzled LDS + gate partials ----
  const int r0 = tid >> 5;  // 0..15
  const int ga = tid & 31;  // k-granule 0..31 (8 f32)
  f32x4 aL[4][2];
#pragma unroll
  for (int q = 0; q < 4; ++q) {
    const int row = r0 + q * 16;
    const int n = min(nb + row, NN - 1);
    const float* sp = (ga < 16) ? (xin + (size_t)n * 128 + ga * 8)
                                : (S + (size_t)n * 128 + (ga - 16) * 8);
    aL[q][0] = __builtin_nontemporal_load((const f32x4*)sp);
    aL[q][1] = __builtin_nontemporal_load((const f32x4*)(sp + 4));
  }
  __syncthreads();  // wgs staged (prologue loads drain here; one-time)

  float gacc[4][4];
#pragma unroll
  for (int q = 0; q < 4; ++q)
#pragma unroll
    for (int e = 0; e < 4; ++e) gacc[q][e] = 0.f;
#pragma unroll
  for (int q = 0; q < 4; ++q) {
    const int row = r0 + q * 16;
    const f32x4 v0 = aL[q][0], v1 = aL[q][1];
    const float vv[8] = {v0[0], v0[1], v0[2], v0[3], v1[0], v1[1], v1[2], v1[3]};
    bfx8 hv, lv;
#pragma unroll
    for (int i = 0; i < 8; ++i) {
      const int k = ga * 8 + i;
#pragma unroll
      for (int e = 0; e < 4; ++e) gacc[q][e] += vv[i] * wgs[e * 256 + k];
      ushort h = f2bf(vv[i]);
      float hf = __uint_as_float(((unsigned int)h) << 16);
      hv[i] = (short)h;
      lv[i] = (short)f2bf(vv[i] - hf);
    }
    const int gsw = (ga ^ (row & 7)) * 8;
    *(bfx8*)&Ahi[row * 256 + gsw] = hv;
    *(bfx8*)&Alo[row * 256 + gsw] = lv;
  }
#pragma unroll
  for (int q = 0; q < 4; ++q) {
#pragma unroll
    for (int mask = 1; mask < 32; mask <<= 1) {
#pragma unroll
      for (int e = 0; e < 4; ++e) gacc[q][e] += __shfl_xor(gacc[q][e], mask);
    }
  }
  if ((tid & 31) == 0) {
#pragma unroll
    for (int q = 0; q < 4; ++q) {
      const int row = r0 + q * 16;
      float g0 = gacc[q][0] + gbs[0], g1 = gacc[q][1] + gbs[1];
      float g2 = gacc[q][2] + gbs[2], g3 = gacc[q][3] + gbs[3];
      float m = fmaxf(fmaxf(g0, g1), fmaxf(g2, g3));
      float e0 = expf(g0 - m), e1 = expf(g1 - m), e2 = expf(g2 - m), e3 = expf(g3 - m);
      float si = 1.0f / (e0 + e1 + e2 + e3);
      gts[row * 4 + 0] = e0 * si;
      gts[row * 4 + 1] = e1 * si;
      gts[row * 4 + 2] = e2 * si;
      gts[row * 4 + 3] = e3 * si;
    }
  }
  __syncthreads();  // A + gts visible; LDS is read-only from here on — no more barriers

  // ---- main loop: barrier-free; B fragments direct from global (L2-resident) ----
  f32x4 res[2][2];
#pragma unroll
  for (int m = 0; m < 2; ++m)
#pragma unroll
    for (int f = 0; f < 2; ++f) res[m][f] = (f32x4){0.f, 0.f, 0.f, 0.f};

#pragma unroll
  for (int e = 0; e < 4; ++e) {
    const ushort* wh = Whi + e * 32768;
    const ushort* wl = Wlo + e * 32768;
    f32x4 acc[2][2];
#pragma unroll
    for (int m = 0; m < 2; ++m)
#pragma unroll
      for (int f = 0; f < 2; ++f) acc[m][f] = (f32x4){0.f, 0.f, 0.f, 0.f};

#pragma unroll
    for (int c = 0; c < 4; ++c) {
#pragma unroll
      for (int ks = 0; ks < 2; ++ks) {
        bfx8 ah[2], al[2];
#pragma unroll
        for (int m = 0; m < 2; ++m) {
          const int ar = wr * 32 + m * 16 + cl;
          const int gi = ((c * 8 + ks * 4 + kg) ^ (ar & 7)) * 8;
          ah[m] = *(const bfx8*)&Ahi[ar * 256 + gi];
          al[m] = *(const bfx8*)&Alo[ar * 256 + gi];
        }
        const int kgo = c * 64 + (ks * 4 + kg) * 8;
#pragma unroll
        for (int f = 0; f < 2; ++f) {
          const int o = wc * 32 + f * 16 + cl;
          const bfx8 bh = *(const bfx8*)&wh[o * 256 + kgo];
          const bfx8 bl = *(const bfx8*)&wl[o * 256 + kgo];
#pragma unroll
          for (int m = 0; m < 2; ++m) {
            acc[m][f] = __builtin_amdgcn_mfma_f32_16x16x32_bf16(ah[m], bh, acc[m][f], 0, 0, 0);
            acc[m][f] = __builtin_amdgcn_mfma_f32_16x16x32_bf16(ah[m], bl, acc[m][f], 0, 0, 0);
            acc[m][f] = __builtin_amdgcn_mfma_f32_16x16x32_bf16(al[m], bh, acc[m][f], 0, 0, 0);
          }
        }
      }
    }
    // expert epilogue: bias + relu + gated accumulate
    const float b0 = aggbs[e * 128 + wc * 32 + cl];
    const float b1 = aggbs[e * 128 + wc * 32 + 16 + cl];
#pragma unroll
    for (int m = 0; m < 2; ++m) {
#pragma unroll
      for (int r = 0; r < 4; ++r) {
        const int node = wr * 32 + m * 16 + kg * 4 + r;
        const float g = gts[node * 4 + e];
        res[m][0][r] += g * fmaxf(acc[m][0][r] + b0, 0.f);
        res[m][1][r] += g * fmaxf(acc[m][1][r] + b1, 0.f);
      }
    }
  }

  // ---- per-node L2 norm: reduce 16 cl-lanes, then 4 wc-waves via LDS ----
#pragma unroll
  for (int m = 0; m < 2; ++m) {
    f32x4 ss;
#pragma unroll
    for (int r = 0; r < 4; ++r)
      ss[r] = res[m][0][r] * res[m][0][r] + res[m][1][r] * res[m][1][r];
#pragma unroll
    for (int mask = 1; mask < 16; mask <<= 1) {
#pragma unroll
      for (int r = 0; r < 4; ++r) ss[r] += __shfl_xor(ss[r], mask);
    }
    if (cl == 0) {
#pragma unroll
      for (int r = 0; r < 4; ++r) red[wc * 64 + wr * 32 + m * 16 + kg * 4 + r] = ss[r];
    }
  }
  __syncthreads();
#pragma unroll
  for (int m = 0; m < 2; ++m) {
#pragma unroll
    for (int r = 0; r < 4; ++r) {
      const int node = wr * 32 + m * 16 + kg * 4 + r;
      const int n = nb + node;
      if (n >= NN) continue;
      const float t = red[node] + red[64 + node] + red[128 + node] + red[192 + node];
      const float inv = 1.0f / fmaxf(sqrtf(t), 1e-12f);
      hout[(size_t)n * 128 + wc * 32 + cl]      = fmaxf(res[m][0][r] * inv, 0.f);
      hout[(size_t)n * 128 + wc * 32 + 16 + cl] = fmaxf(res[m][1][r] * inv, 0.f);
    }
  }
}

// ---------------- post2 + log_softmax ----------------
__global__ void post2_kernel(const float* __restrict__ P, const float* __restrict__ W2,
                             const float* __restrict__ b2, float* __restrict__ out) {
  __shared__ __align__(16) float ps[32 * 132];
  __shared__ __align__(16) float w2s[40 * 132];
  __shared__ float b2s[40];
  const int tid = threadIdx.x;
  const int nb = blockIdx.x * 32;
  for (int i = tid; i < 5120; i += 256) {
    int o = i >> 7, k = i & 127;
    w2s[o * 132 + k] = W2[i];
  }
  if (tid < 40) b2s[tid] = b2[tid];
  {
    const int k = tid & 127;
    const int nl0 = tid >> 7;
#pragma unroll
    for (int r = 0; r < 16; ++r) {
      int nl = r * 2 + nl0;
      int n = min(nb + nl, NN - 1);
      ps[nl * 132 + k] = P[n * 128 + k];
    }
  }
  __syncthreads();

  const int nl = tid >> 3, g = tid & 7;
  float acc[5] = {0.f, 0.f, 0.f, 0.f, 0.f};
  for (int k = 0; k < 128; k += 4) {
    const float4 pv = *(const float4*)&ps[nl * 132 + k];
#pragma unroll
    for (int j = 0; j < 5; ++j) {
      const int o = g * 5 + j;
      const float4 wv = *(const float4*)&w2s[o * 132 + k];
      acc[j] += pv.x * wv.x + pv.y * wv.y + pv.z * wv.z + pv.w * wv.w;
    }
  }
  float l[5];
  float m = -1e30f;
#pragma unroll
  for (int j = 0; j < 5; ++j) {
    l[j] = acc[j] + b2s[g * 5 + j];
    m = fmaxf(m, l[j]);
  }
  m = fmaxf(m, __shfl_xor(m, 1, 8));
  m = fmaxf(m, __shfl_xor(m, 2, 8));
  m = fmaxf(m, __shfl_xor(m, 4, 8));
  float s = 0.f;
#pragma unroll
  for (int j = 0; j < 5; ++j) s += expf(l[j] - m);
  s += __shfl_xor(s, 1, 8);
  s += __shfl_xor(s, 2, 8);
  s += __shfl_xor(s, 4, 8);
  const float lse = m + logf(s);
  const int n = nb + nl;
  if (n < NN) {
#pragma unroll
    for (int j = 0; j < 5; ++j) out[n * 40 + g * 5 + j] = l[j] - lse;
  }
}

extern "C" void kernel_launch(void* const* d_in, const int* in_sizes, int n_in,
                              void* d_out, int out_size, void* d_ws, size_t ws_size,
                              hipStream_t stream) {
  const float* x       = (const float*)d_in[0];
  const int*   ei      = (const int*)d_in[1];
  const int*   src     = ei;
  const int*   dstp    = ei + NE;
  const float* lin_w0  = (const float*)d_in[2];
  const float* lin_b0  = (const float*)d_in[3];
  const float* agg_w0  = (const float*)d_in[4];
  const float* agg_b0  = (const float*)d_in[5];
  const float* gate_w0 = (const float*)d_in[6];
  const float* gate_b0 = (const float*)d_in[7];
  const float* lin_w1  = (const float*)d_in[8];
  const float* lin_b1  = (const float*)d_in[9];
  const float* agg_w1  = (const float*)d_in[10];
  const float* agg_b1  = (const float*)d_in[11];
  const float* gate_w1 = (const float*)d_in[12];
  const float* gate_b1 = (const float*)d_in[13];
  const float* post_w1 = (const float*)d_in[14];
  const float* post_b1 = (const float*)d_in[15];
  const float* post_w2 = (const float*)d_in[16];
  const float* post_b2 = (const float*)d_in[17];

  float* A  = (float*)d_ws;     // lin output per layer; reused as H2
  float* Sb = A + 6400000;      // aggregated means; reused as P
  float* H1 = Sb + 6400000;
  ushort* WHIa = (ushort*)(H1 + 6400000);  // [2][4][128][256] agg weights hi
  ushort* WLOa = WHIa + 262144;
  ushort* WHIl = WLOa + 262144;            // [3][128][128] lin0,lin1,post1 hi
  ushort* WLOl = WHIl + 49152;
  unsigned int* CNT      = (unsigned int*)(WLOl + 49152);  // becomes cursor
  unsigned int* ROWSTART = CNT + NN;
  unsigned int* BSUM     = ROWSTART + NN + 1;
  int*          ESRC     = (int*)(BSUM + 256);

  const int gridN64 = (NN + 63) / 64;  // 782

  // ---- CSR build (hierarchical scan) + weight pre-convert ----
  (void)hipMemsetAsync(CNT, 0, NN * sizeof(unsigned int), stream);
  count_kernel<<<NE / 256, 256, 0, stream>>>(dstp, CNT);
  partial_kernel<<<NBLK_SCAN, 256, 0, stream>>>(CNT, BSUM);
  scanb_kernel<<<1, 256, 0, stream>>>(BSUM);
  apply_kernel<<<NBLK_SCAN, 256, 0, stream>>>(CNT, BSUM, ROWSTART);
  bucket_kernel<<<NE / 256, 256, 0, stream>>>(src, dstp, CNT, ESRC);
  wconv_kernel<<<512, 256, 0, stream>>>(agg_w0, WHIa, WLOa, 131072);
  wconv_kernel<<<512, 256, 0, stream>>>(agg_w1, WHIa + 131072, WLOa + 131072, 131072);
  wconv_kernel<<<64, 256, 0, stream>>>(lin_w0, WHIl, WLOl, 16384);
  wconv_kernel<<<64, 256, 0, stream>>>(lin_w1, WHIl + 16384, WLOl + 16384, 16384);
  wconv_kernel<<<64, 256, 0, stream>>>(post_w1, WHIl + 32768, WLOl + 32768, 16384);

  // ---- layer 0 ----
  linm_kernel<1><<<gridN64, 256, 0, stream>>>(x, WHIl, WLOl, lin_b0, A);
  aggregate_kernel<<<(NN * 32 + 255) / 256, 256, 0, stream>>>(A, ESRC, ROWSTART, Sb);
  update_kernel<<<gridN64, 512, 0, stream>>>(x, Sb, gate_w0, gate_b0, WHIa, WLOa, agg_b0, H1);

  // ---- layer 1 ----
  linm_kernel<1><<<gridN64, 256, 0, stream>>>(H1, WHIl + 16384, WLOl + 16384, lin_b1, A);
  aggregate_kernel<<<(NN * 32 + 255) / 256, 256, 0, stream>>>(A, ESRC, ROWSTART, Sb);
  update_kernel<<<gridN64, 512, 0, stream>>>(H1, Sb, gate_w1, gate_b1, WHIa + 131072,
                                             WLOa + 131072, agg_b1, A);

  // ---- post MLP + log_softmax ----
  linm_kernel<0><<<gridN64, 256, 0, stream>>>(A, WHIl + 32768, WLOl + 32768, post_b1, Sb);
  post2_kernel<<<(NN + 31) / 32, 256, 0, stream>>>(Sb, post_w2, post_b2, (float*)d_out);
}

// Round 12
// 676.384 us; speedup vs baseline: 1.0246x; 1.0246x over previous
//
#include <hip/hip_runtime.h>
#include <hip/hip_bf16.h>
#include <cmath>

#define NN 50000
#define NE 800000
#define NBLK_SCAN 196  // ceil(NN/256)

typedef __attribute__((ext_vector_type(4))) float f32x4;
typedef __attribute__((ext_vector_type(8))) short bfx8;

__device__ inline ushort f2bf(float x) {
  return __bfloat16_as_ushort(__float2bfloat16(x));
}

// Raw barrier: lgkmcnt(0) + s_barrier, no vmcnt drain (keeps prefetch loads in flight).
#define BAR_NODRAIN() asm volatile("s_waitcnt lgkmcnt(0)\ns_barrier" ::: "memory")

// ---------------- CSR build ----------------
__global__ void count_kernel(const int* __restrict__ dst, unsigned int* __restrict__ cnt) {
  int e = blockIdx.x * 256 + threadIdx.x;
  if (e < NE) atomicAdd(&cnt[dst[e]], 1u);
}

__global__ void partial_kernel(const unsigned int* __restrict__ cnt,
                               unsigned int* __restrict__ bsum) {
  __shared__ unsigned int s[256];
  const int t = threadIdx.x;
  const int i = blockIdx.x * 256 + t;
  s[t] = (i < NN) ? cnt[i] : 0u;
  __syncthreads();
#pragma unroll
  for (int o = 128; o > 0; o >>= 1) {
    if (t < o) s[t] += s[t + o];
    __syncthreads();
  }
  if (t == 0) bsum[blockIdx.x] = s[0];
}

__global__ void scanb_kernel(unsigned int* __restrict__ bsum) {
  __shared__ unsigned int s[256];
  const int t = threadIdx.x;
  const unsigned int v = (t < NBLK_SCAN) ? bsum[t] : 0u;
  s[t] = v;
  __syncthreads();
  for (int o = 1; o < 256; o <<= 1) {
    unsigned int u = (t >= o) ? s[t - o] : 0u;
    __syncthreads();
    s[t] += u;
    __syncthreads();
  }
  if (t < NBLK_SCAN) bsum[t] = s[t] - v;  // exclusive
}

__global__ void apply_kernel(unsigned int* __restrict__ cnt,
                             const unsigned int* __restrict__ bsum,
                             unsigned int* __restrict__ rowstart) {
  __shared__ unsigned int s[256];
  const int t = threadIdx.x;
  const int i = blockIdx.x * 256 + t;
  const unsigned int v = (i < NN) ? cnt[i] : 0u;
  s[t] = v;
  __syncthreads();
  for (int o = 1; o < 256; o <<= 1) {
    unsigned int u = (t >= o) ? s[t - o] : 0u;
    __syncthreads();
    s[t] += u;
    __syncthreads();
  }
  const unsigned int excl = s[t] - v + bsum[blockIdx.x];
  if (i < NN) {
    rowstart[i] = excl;
    cnt[i] = excl;  // cursor
    if (i == NN - 1) rowstart[NN] = excl + v;
  }
}

__global__ void bucket_kernel(const int* __restrict__ src, const int* __restrict__ dst,
                              unsigned int* __restrict__ cursor, int* __restrict__ esrc) {
  int e = blockIdx.x * 256 + threadIdx.x;
  if (e < NE) {
    unsigned int pos = atomicAdd(&cursor[dst[e]], 1u);
    esrc[pos] = src[e];
  }
}

// ---------------- weight pre-convert: f32 -> bf16 hi/lo ----------------
__global__ void wconv_kernel(const float* __restrict__ w, ushort* __restrict__ hi,
                             ushort* __restrict__ lo, int count) {
  int i = blockIdx.x * 256 + threadIdx.x;
  if (i < count) {
    float x = w[i];
    ushort h = f2bf(x);
    float hf = __uint_as_float(((unsigned int)h) << 16);
    hi[i] = h;
    lo[i] = f2bf(x - hf);
  }
}

// ---------------- aggregate: S[n] = mean over edges of A[src] ----------------
__global__ __launch_bounds__(256) void aggregate_kernel(const float* __restrict__ A,
                                                        const int* __restrict__ esrc,
                                                        const unsigned int* __restrict__ rowstart,
                                                        float* __restrict__ S) {
  const int t = blockIdx.x * 256 + threadIdx.x;
  const int node = t >> 5;
  const int lane = t & 31;
  if (node >= NN) return;
  const unsigned int rs = rowstart[node], re = rowstart[node + 1];
  f32x4 acc = (f32x4){0.f, 0.f, 0.f, 0.f};
  unsigned int j = rs;
  for (; j + 4 <= re; j += 4) {
    const int s0 = esrc[j], s1 = esrc[j + 1], s2 = esrc[j + 2], s3 = esrc[j + 3];
    const f32x4 v0 = *(const f32x4*)&A[(size_t)s0 * 128 + lane * 4];
    const f32x4 v1 = *(const f32x4*)&A[(size_t)s1 * 128 + lane * 4];
    const f32x4 v2 = *(const f32x4*)&A[(size_t)s2 * 128 + lane * 4];
    const f32x4 v3 = *(const f32x4*)&A[(size_t)s3 * 128 + lane * 4];
    acc += (v0 + v1) + (v2 + v3);
  }
  for (; j < re; ++j) {
    const int s = esrc[j];
    acc += *(const f32x4*)&A[(size_t)s * 128 + lane * 4];
  }
  const float inv = 1.0f / fmaxf((float)(re - rs), 1.0f);
  *(f32x4*)&S[(size_t)node * 128 + lane * 4] = acc * inv;
}

// ---------------- linm (MFMA): out = act(in @ W^T + b), [NN,128]x[128,128] ----------------
template <int RELU>
__global__ __launch_bounds__(256, 3) void linm_kernel(const float* __restrict__ in,
                                                      const ushort* __restrict__ Whi,
                                                      const ushort* __restrict__ Wlo,
                                                      const float* __restrict__ bias,
                                                      float* __restrict__ out) {
  __shared__ __align__(16) ushort Ahi[64 * 64];
  __shared__ __align__(16) ushort Alo[64 * 64];
  __shared__ __align__(16) ushort Bhi[128 * 64];
  __shared__ __align__(16) ushort Blo[128 * 64];
  __shared__ float bs[128];

  const int tid = threadIdx.x;
  const int nb = blockIdx.x * 64;
  const int lane = tid & 63;
  const int wv = tid >> 6;
  const int cl = lane & 15;
  const int kg = lane >> 4;

  if (tid < 128) bs[tid] = bias[tid];

  f32x4 aP[4];
  bfx8 bP[2][8];

#pragma unroll
  for (int q = 0; q < 2; ++q) {
    const int task = tid + q * 256, row = task >> 3, g = task & 7;
    const int n = min(nb + row, NN - 1);
    aP[q * 2 + 0] = __builtin_nontemporal_load((const f32x4*)&in[(size_t)n * 128 + g * 8]);
    aP[q * 2 + 1] = __builtin_nontemporal_load((const f32x4*)&in[(size_t)n * 128 + g * 8 + 4]);
  }
#pragma unroll
  for (int q = 0; q < 4; ++q) {
    const int task = tid + q * 256, o = task >> 3, g = task & 7;
    bP[0][q * 2 + 0] = *(const bfx8*)&Whi[o * 128 + g * 8];
    bP[0][q * 2 + 1] = *(const bfx8*)&Wlo[o * 128 + g * 8];
  }

  f32x4 acc[4][2];
#pragma unroll
  for (int m = 0; m < 4; ++m)
#pragma unroll
    for (int f = 0; f < 2; ++f) acc[m][f] = (f32x4){0.f, 0.f, 0.f, 0.f};

#pragma unroll
  for (int c = 0; c < 2; ++c) {
    BAR_NODRAIN();
    {
#pragma unroll
      for (int q = 0; q < 2; ++q) {
        const int task = tid + q * 256, row = task >> 3, g = task & 7;
        const f32x4 v0 = aP[q * 2 + 0], v1 = aP[q * 2 + 1];
        const float vv[8] = {v0[0], v0[1], v0[2], v0[3], v1[0], v1[1], v1[2], v1[3]};
        bfx8 hv, lv;
#pragma unroll
        for (int i = 0; i < 8; ++i) {
          ushort h = f2bf(vv[i]);
          float hf = __uint_as_float(((unsigned int)h) << 16);
          hv[i] = (short)h;
          lv[i] = (short)f2bf(vv[i] - hf);
        }
        const int gsw = (g ^ (row & 7)) * 8;
        *(bfx8*)&Ahi[row * 64 + gsw] = hv;
        *(bfx8*)&Alo[row * 64 + gsw] = lv;
      }
    }
    {
#pragma unroll
      for (int q = 0; q < 4; ++q) {
        const int task = tid + q * 256, o = task >> 3, g = task & 7;
        const int gsw = (g ^ (o & 7)) * 8;
        *(bfx8*)&Bhi[o * 64 + gsw] = bP[c][q * 2 + 0];
        *(bfx8*)&Blo[o * 64 + gsw] = bP[c][q * 2 + 1];
      }
    }
    if (c == 0) {
#pragma unroll
      for (int q = 0; q < 2; ++q) {
        const int task = tid + q * 256, row = task >> 3, g = task & 7;
        const int n = min(nb + row, NN - 1);
        aP[q * 2 + 0] = __builtin_nontemporal_load((const f32x4*)&in[(size_t)n * 128 + 64 + g * 8]);
        aP[q * 2 + 1] = __builtin_nontemporal_load((const f32x4*)&in[(size_t)n * 128 + 64 + g * 8 + 4]);
      }
#pragma unroll
      for (int q = 0; q < 4; ++q) {
        const int task = tid + q * 256, o = task >> 3, g = task & 7;
        bP[1][q * 2 + 0] = *(const bfx8*)&Whi[o * 128 + 64 + g * 8];
        bP[1][q * 2 + 1] = *(const bfx8*)&Wlo[o * 128 + 64 + g * 8];
      }
    }
    BAR_NODRAIN();
#pragma unroll
    for (int ks = 0; ks < 2; ++ks) {
      bfx8 ah[4], al[4];
#pragma unroll
      for (int m = 0; m < 4; ++m) {
        const int ar = m * 16 + cl;
        const int gi = ((ks * 4 + kg) ^ (ar & 7)) * 8;
        ah[m] = *(const bfx8*)&Ahi[ar * 64 + gi];
        al[m] = *(const bfx8*)&Alo[ar * 64 + gi];
      }
#pragma unroll
      for (int f = 0; f < 2; ++f) {
        const int o = wv * 32 + f * 16 + cl;
        const int gi = ((ks * 4 + kg) ^ (o & 7)) * 8;
        const bfx8 bh = *(const bfx8*)&Bhi[o * 64 + gi];
        const bfx8 bl = *(const bfx8*)&Blo[o * 64 + gi];
#pragma unroll
        for (int m = 0; m < 4; ++m) {
          acc[m][f] = __builtin_amdgcn_mfma_f32_16x16x32_bf16(ah[m], bh, acc[m][f], 0, 0, 0);
          acc[m][f] = __builtin_amdgcn_mfma_f32_16x16x32_bf16(ah[m], bl, acc[m][f], 0, 0, 0);
          acc[m][f] = __builtin_amdgcn_mfma_f32_16x16x32_bf16(al[m], bh, acc[m][f], 0, 0, 0);
        }
      }
    }
  }

#pragma unroll
  for (int m = 0; m < 4; ++m) {
#pragma unroll
    for (int r = 0; r < 4; ++r) {
      const int node = m * 16 + kg * 4 + r;
      const int n = nb + node;
      if (n >= NN) continue;
#pragma unroll
      for (int f = 0; f < 2; ++f) {
        const int col = wv * 32 + f * 16 + cl;
        float v = acc[m][f][r] + bs[col];
        if (RELU) v = fmaxf(v, 0.f);
        out[(size_t)n * 128 + col] = v;
      }
    }
  }
}

// ---------------- update v5 (MFMA): barrier-free, B from L2, spill-free regs ----------------
// 512 threads = 8 waves (2M x 4N). A [64][256] hi/lo staged ONCE in LDS; B fragments
// per-lane direct global loads (weights L2-resident). __launch_bounds__(512,2): 256-reg
// cap (no spill; AGPR granule leaves VGPR room). e/c loops unroll(1) to cap in-flight loads.
__global__ __launch_bounds__(512, 2) void update_kernel(
    const float* __restrict__ xin, const float* __restrict__ S,
    const float* __restrict__ gw, const float* __restrict__ gb,
    const ushort* __restrict__ Whi, const ushort* __restrict__ Wlo,
    const float* __restrict__ aggb, float* __restrict__ hout) {
  __shared__ __align__(16) ushort Ahi[64 * 256];  // 32KB
  __shared__ __align__(16) ushort Alo[64 * 256];  // 32KB
  __shared__ float wgs[1024];
  __shared__ float gbs[4];
  __shared__ float aggbs[512];
  __shared__ float gts[256];
  __shared__ float red[4 * 64];

  const int tid = threadIdx.x;
  const int nb = blockIdx.x * 64;
  const int lane = tid & 63;
  const int wv = tid >> 6;  // 0..7
  const int wr = wv >> 2;   // M-group 0..1
  const int wc = wv & 3;    // N-group 0..3
  const int cl = lane & 15;
  const int kg = lane >> 4;

  for (int i = tid; i < 1024; i += 512) wgs[i] = gw[i];
  if (tid < 512) aggbs[tid] = aggb[tid];
  if (tid < 4) gbs[tid] = gb[tid];

  // ---- stage A (once): global -> f32, convert hi/lo, swizzled LDS + gate partials ----
  const int r0 = tid >> 5;  // 0..15
  const int ga = tid & 31;  // k-granule 0..31 (8 f32)
  f32x4 aL[4][2];
#pragma unroll
  for (int q = 0; q < 4; ++q) {
    const int row = r0 + q * 16;
    const int n = min(nb + row, NN - 1);
    const float* sp = (ga < 16) ? (xin + (size_t)n * 128 + ga * 8)
                                : (S + (size_t)n * 128 + (ga - 16) * 8);
    aL[q][0] = __builtin_nontemporal_load((const f32x4*)sp);
    aL[q][1] = __builtin_nontemporal_load((const f32x4*)(sp + 4));
  }
  __syncthreads();  // wgs staged (prologue loads drain here; one-time)

  float gacc[4][4];
#pragma unroll
  for (int q = 0; q < 4; ++q)
#pragma unroll
    for (int e = 0; e < 4; ++e) gacc[q][e] = 0.f;
#pragma unroll
  for (int q = 0; q < 4; ++q) {
    const int row = r0 + q * 16;
    const f32x4 v0 = aL[q][0], v1 = aL[q][1];
    const float vv[8] = {v0[0], v0[1], v0[2], v0[3], v1[0], v1[1], v1[2], v1[3]};
    bfx8 hv, lv;
#pragma unroll
    for (int i = 0; i < 8; ++i) {
      const int k = ga * 8 + i;
#pragma unroll
      for (int e = 0; e < 4; ++e) gacc[q][e] += vv[i] * wgs[e * 256 + k];
      ushort h = f2bf(vv[i]);
      float hf = __uint_as_float(((unsigned int)h) << 16);
      hv[i] = (short)h;
      lv[i] = (short)f2bf(vv[i] - hf);
    }
    const int gsw = (ga ^ (row & 7)) * 8;
    *(bfx8*)&Ahi[row * 256 + gsw] = hv;
    *(bfx8*)&Alo[row * 256 + gsw] = lv;
  }
#pragma unroll
  for (int q = 0; q < 4; ++q) {
#pragma unroll
    for (int mask = 1; mask < 32; mask <<= 1) {
#pragma unroll
      for (int e = 0; e < 4; ++e) gacc[q][e] += __shfl_xor(gacc[q][e], mask);
    }
  }
  if ((tid & 31) == 0) {
#pragma unroll
    for (int q = 0; q < 4; ++q) {
      const int row = r0 + q * 16;
      float g0 = gacc[q][0] + gbs[0], g1 = gacc[q][1] + gbs[1];
      float g2 = gacc[q][2] + gbs[2], g3 = gacc[q][3] + gbs[3];
      float m = fmaxf(fmaxf(g0, g1), fmaxf(g2, g3));
      float e0 = expf(g0 - m), e1 = expf(g1 - m), e2 = expf(g2 - m), e3 = expf(g3 - m);
      float si = 1.0f / (e0 + e1 + e2 + e3);
      gts[row * 4 + 0] = e0 * si;
      gts[row * 4 + 1] = e1 * si;
      gts[row * 4 + 2] = e2 * si;
      gts[row * 4 + 3] = e3 * si;
    }
  }
  __syncthreads();  // A + gts visible; LDS read-only from here — no more barriers

  // ---- main loop: barrier-free; B fragments direct from global (L2-resident) ----
  f32x4 res[2][2];
#pragma unroll
  for (int m = 0; m < 2; ++m)
#pragma unroll
    for (int f = 0; f < 2; ++f) res[m][f] = (f32x4){0.f, 0.f, 0.f, 0.f};

#pragma unroll 1
  for (int e = 0; e < 4; ++e) {
    const ushort* wh = Whi + e * 32768;
    const ushort* wl = Wlo + e * 32768;
    f32x4 acc[2][2];
#pragma unroll
    for (int m = 0; m < 2; ++m)
#pragma unroll
      for (int f = 0; f < 2; ++f) acc[m][f] = (f32x4){0.f, 0.f, 0.f, 0.f};

#pragma unroll 1
    for (int c = 0; c < 4; ++c) {
#pragma unroll
      for (int ks = 0; ks < 2; ++ks) {
        bfx8 ah[2], al[2];
#pragma unroll
        for (int m = 0; m < 2; ++m) {
          const int ar = wr * 32 + m * 16 + cl;
          const int gi = ((c * 8 + ks * 4 + kg) ^ (ar & 7)) * 8;
          ah[m] = *(const bfx8*)&Ahi[ar * 256 + gi];
          al[m] = *(const bfx8*)&Alo[ar * 256 + gi];
        }
        const int kgo = c * 64 + (ks * 4 + kg) * 8;
#pragma unroll
        for (int f = 0; f < 2; ++f) {
          const int o = wc * 32 + f * 16 + cl;
          const bfx8 bh = *(const bfx8*)&wh[o * 256 + kgo];
          const bfx8 bl = *(const bfx8*)&wl[o * 256 + kgo];
#pragma unroll
          for (int m = 0; m < 2; ++m) {
            acc[m][f] = __builtin_amdgcn_mfma_f32_16x16x32_bf16(ah[m], bh, acc[m][f], 0, 0, 0);
            acc[m][f] = __builtin_amdgcn_mfma_f32_16x16x32_bf16(ah[m], bl, acc[m][f], 0, 0, 0);
            acc[m][f] = __builtin_amdgcn_mfma_f32_16x16x32_bf16(al[m], bh, acc[m][f], 0, 0, 0);
          }
        }
      }
    }
    // expert epilogue: bias + relu + gated accumulate
    const float b0 = aggbs[e * 128 + wc * 32 + cl];
    const float b1 = aggbs[e * 128 + wc * 32 + 16 + cl];
#pragma unroll
    for (int m = 0; m < 2; ++m) {
#pragma unroll
      for (int r = 0; r < 4; ++r) {
        const int node = wr * 32 + m * 16 + kg * 4 + r;
        const float g = gts[node * 4 + e];
        res[m][0][r] += g * fmaxf(acc[m][0][r] + b0, 0.f);
        res[m][1][r] += g * fmaxf(acc[m][1][r] + b1, 0.f);
      }
    }
  }

  // ---- per-node L2 norm: reduce 16 cl-lanes, then 4 wc-waves via LDS ----
#pragma unroll
  for (int m = 0; m < 2; ++m) {
    f32x4 ss;
#pragma unroll
    for (int r = 0; r < 4; ++r)
      ss[r] = res[m][0][r] * res[m][0][r] + res[m][1][r] * res[m][1][r];
#pragma unroll
    for (int mask = 1; mask < 16; mask <<= 1) {
#pragma unroll
      for (int r = 0; r < 4; ++r) ss[r] += __shfl_xor(ss[r], mask);
    }
    if (cl == 0) {
#pragma unroll
      for (int r = 0; r < 4; ++r) red[wc * 64 + wr * 32 + m * 16 + kg * 4 + r] = ss[r];
    }
  }
  __syncthreads();
#pragma unroll
  for (int m = 0; m < 2; ++m) {
#pragma unroll
    for (int r = 0; r < 4; ++r) {
      const int node = wr * 32 + m * 16 + kg * 4 + r;
      const int n = nb + node;
      if (n >= NN) continue;
      const float t = red[node] + red[64 + node] + red[128 + node] + red[192 + node];
      const float inv = 1.0f / fmaxf(sqrtf(t), 1e-12f);
      hout[(size_t)n * 128 + wc * 32 + cl]      = fmaxf(res[m][0][r] * inv, 0.f);
      hout[(size_t)n * 128 + wc * 32 + 16 + cl] = fmaxf(res[m][1][r] * inv, 0.f);
    }
  }
}

// ---------------- post2 + log_softmax ----------------
__global__ void post2_kernel(const float* __restrict__ P, const float* __restrict__ W2,
                             const float* __restrict__ b2, float* __restrict__ out) {
  __shared__ __align__(16) float ps[32 * 132];
  __shared__ __align__(16) float w2s[40 * 132];
  __shared__ float b2s[40];
  const int tid = threadIdx.x;
  const int nb = blockIdx.x * 32;
  for (int i = tid; i < 5120; i += 256) {
    int o = i >> 7, k = i & 127;
    w2s[o * 132 + k] = W2[i];
  }
  if (tid < 40) b2s[tid] = b2[tid];
  {
    const int k = tid & 127;
    const int nl0 = tid >> 7;
#pragma unroll
    for (int r = 0; r < 16; ++r) {
      int nl = r * 2 + nl0;
      int n = min(nb + nl, NN - 1);
      ps[nl * 132 + k] = P[n * 128 + k];
    }
  }
  __syncthreads();

  const int nl = tid >> 3, g = tid & 7;
  float acc[5] = {0.f, 0.f, 0.f, 0.f, 0.f};
  for (int k = 0; k < 128; k += 4) {
    const float4 pv = *(const float4*)&ps[nl * 132 + k];
#pragma unroll
    for (int j = 0; j < 5; ++j) {
      const int o = g * 5 + j;
      const float4 wv = *(const float4*)&w2s[o * 132 + k];
      acc[j] += pv.x * wv.x + pv.y * wv.y + pv.z * wv.z + pv.w * wv.w;
    }
  }
  float l[5];
  float m = -1e30f;
#pragma unroll
  for (int j = 0; j < 5; ++j) {
    l[j] = acc[j] + b2s[g * 5 + j];
    m = fmaxf(m, l[j]);
  }
  m = fmaxf(m, __shfl_xor(m, 1, 8));
  m = fmaxf(m, __shfl_xor(m, 2, 8));
  m = fmaxf(m, __shfl_xor(m, 4, 8));
  float s = 0.f;
#pragma unroll
  for (int j = 0; j < 5; ++j) s += expf(l[j] - m);
  s += __shfl_xor(s, 1, 8);
  s += __shfl_xor(s, 2, 8);
  s += __shfl_xor(s, 4, 8);
  const float lse = m + logf(s);
  const int n = nb + nl;
  if (n < NN) {
#pragma unroll
    for (int j = 0; j < 5; ++j) out[n * 40 + g * 5 + j] = l[j] - lse;
  }
}

extern "C" void kernel_launch(void* const* d_in, const int* in_sizes, int n_in,
                              void* d_out, int out_size, void* d_ws, size_t ws_size,
                              hipStream_t stream) {
  const float* x       = (const float*)d_in[0];
  const int*   ei      = (const int*)d_in[1];
  const int*   src     = ei;
  const int*   dstp    = ei + NE;
  const float* lin_w0  = (const float*)d_in[2];
  const float* lin_b0  = (const float*)d_in[3];
  const float* agg_w0  = (const float*)d_in[4];
  const float* agg_b0  = (const float*)d_in[5];
  const float* gate_w0 = (const float*)d_in[6];
  const float* gate_b0 = (const float*)d_in[7];
  const float* lin_w1  = (const float*)d_in[8];
  const float* lin_b1  = (const float*)d_in[9];
  const float* agg_w1  = (const float*)d_in[10];
  const float* agg_b1  = (const float*)d_in[11];
  const float* gate_w1 = (const float*)d_in[12];
  const float* gate_b1 = (const float*)d_in[13];
  const float* post_w1 = (const float*)d_in[14];
  const float* post_b1 = (const float*)d_in[15];
  const float* post_w2 = (const float*)d_in[16];
  const float* post_b2 = (const float*)d_in[17];

  float* A  = (float*)d_ws;     // lin output per layer; reused as H2
  float* Sb = A + 6400000;      // aggregated means; reused as P
  float* H1 = Sb + 6400000;
  ushort* WHIa = (ushort*)(H1 + 6400000);  // [2][4][128][256] agg weights hi
  ushort* WLOa = WHIa + 262144;
  ushort* WHIl = WLOa + 262144;            // [3][128][128] lin0,lin1,post1 hi
  ushort* WLOl = WHIl + 49152;
  unsigned int* CNT      = (unsigned int*)(WLOl + 49152);  // becomes cursor
  unsigned int* ROWSTART = CNT + NN;
  unsigned int* BSUM     = ROWSTART + NN + 1;
  int*          ESRC     = (int*)(BSUM + 256);

  const int gridN64 = (NN + 63) / 64;  // 782

  // ---- CSR build (hierarchical scan) + weight pre-convert ----
  (void)hipMemsetAsync(CNT, 0, NN * sizeof(unsigned int), stream);
  count_kernel<<<NE / 256, 256, 0, stream>>>(dstp, CNT);
  partial_kernel<<<NBLK_SCAN, 256, 0, stream>>>(CNT, BSUM);
  scanb_kernel<<<1, 256, 0, stream>>>(BSUM);
  apply_kernel<<<NBLK_SCAN, 256, 0, stream>>>(CNT, BSUM, ROWSTART);
  bucket_kernel<<<NE / 256, 256, 0, stream>>>(src, dstp, CNT, ESRC);
  wconv_kernel<<<512, 256, 0, stream>>>(agg_w0, WHIa, WLOa, 131072);
  wconv_kernel<<<512, 256, 0, stream>>>(agg_w1, WHIa + 131072, WLOa + 131072, 131072);
  wconv_kernel<<<64, 256, 0, stream>>>(lin_w0, WHIl, WLOl, 16384);
  wconv_kernel<<<64, 256, 0, stream>>>(lin_w1, WHIl + 16384, WLOl + 16384, 16384);
  wconv_kernel<<<64, 256, 0, stream>>>(post_w1, WHIl + 32768, WLOl + 32768, 16384);

  // ---- layer 0 ----
  linm_kernel<1><<<gridN64, 256, 0, stream>>>(x, WHIl, WLOl, lin_b0, A);
  aggregate_kernel<<<(NN * 32 + 255) / 256, 256, 0, stream>>>(A, ESRC, ROWSTART, Sb);
  update_kernel<<<gridN64, 512, 0, stream>>>(x, Sb, gate_w0, gate_b0, WHIa, WLOa, agg_b0, H1);

  // ---- layer 1 ----
  linm_kernel<1><<<gridN64, 256, 0, stream>>>(H1, WHIl + 16384, WLOl + 16384, lin_b1, A);
  aggregate_kernel<<<(NN * 32 + 255) / 256, 256, 0, stream>>>(A, ESRC, ROWSTART, Sb);
  update_kernel<<<gridN64, 512, 0, stream>>>(H1, Sb, gate_w1, gate_b1, WHIa + 131072,
                                             WLOa + 131072, agg_b1, A);

  // ---- post MLP + log_softmax ----
  linm_kernel<0><<<gridN64, 256, 0, stream>>>(A, WHIl + 32768, WLOl + 32768, post_b1, Sb);
  post2_kernel<<<(NN + 31) / 32, 256, 0, stream>>>(Sb, post_w2, post_b2, (float*)d_out);
}